// Round 2
// baseline (571.665 us; speedup 1.0000x reference)
//
#include <hip/hip_runtime.h>

// SphereSampler: gather formulation, 4 voxels per thread (x-consecutive),
// float4 stores, wave-level sphere culling via ballot. Noise is loaded only
// in the +/-4-voxel shell around each sphere surface (|noise|<=8 margin),
// as an aligned float4 per thread when any of its 4 voxels is in-shell.
// Per-voxel math (fmaf(nz,0.5f,r); d2 <= rad*rad) is bit-exact vs the jnp
// reference (verified: absmax 0.0 in round 1).

#define DIMW 128
#define SPHERE_STRIDE (DIMW * DIMW * DIMW)  // 2^21 floats per sphere
#define N_SPHERES 64

__global__ __launch_bounds__(256) void sphere_sampler_kernel(
    const float* __restrict__ noise,   // [64, 128,128,128]
    const float* __restrict__ labels,  // [64]
    const int*   __restrict__ centers, // [64,3] (z,y,x)
    const int*   __restrict__ radii,   // [64]
    float*       __restrict__ out)     // [128,128,128]
{
    const int tid  = threadIdx.x;
    const int lane = tid & 63;
    const int base = blockIdx.x << 10;          // 1024 voxels per block
    const int vidx = base + (tid << 2);         // first of 4 x-consecutive voxels
    const int x0 = vidx & 127;
    const int y  = (vidx >> 7) & 127;
    const int z  = vidx >> 14;

    // Lane s caches sphere s's metadata (64 spheres == 64 lanes).
    const int   cz  = centers[3 * lane + 0];
    const int   cy  = centers[3 * lane + 1];
    const int   cx  = centers[3 * lane + 2];
    const int   r   = radii[lane];
    const float lab = labels[lane];

    // Block footprint: one z-slice row-group, y in [by0, by0+7], full x span.
    const int bz  = base >> 14;
    const int by0 = (base >> 7) & 127;
    int ddz = bz - cz; if (ddz < 0) ddz = -ddz;
    int ddy = 0;
    if      (cy < by0)     ddy = by0 - cy;
    else if (cy > by0 + 7) ddy = cy - (by0 + 7);
    const int rm = r + 4;                       // noise margin: |nz| <= 8
    const bool hit = (ddz * ddz + ddy * ddy) <= rm * rm;
    unsigned long long mask = __ballot(hit);    // wave-uniform sphere list

    float v0 = 0.0f, v1 = 0.0f, v2 = 0.0f, v3 = 0.0f;
    while (mask) {
        const int s = __builtin_ctzll(mask);    // ascending s => last-wins ok
        mask &= mask - 1;
        const int   scz  = __shfl(cz,  s);
        const int   scy  = __shfl(cy,  s);
        const int   scx  = __shfl(cx,  s);
        const int   sr   = __shfl(r,   s);
        const float slab = __shfl(lab, s);

        const int dzz = z - scz;
        const int dyy = y - scy;
        const int zy2 = dzz * dzz + dyy * dyy;
        const int dx0 = x0 - scx;
        const int ro2 = (sr + 4) * (sr + 4);
        const int ri2 = (sr - 4) * (sr - 4);

        int d2_0 = zy2 + (dx0 + 0) * (dx0 + 0);
        int d2_1 = zy2 + (dx0 + 1) * (dx0 + 1);
        int d2_2 = zy2 + (dx0 + 2) * (dx0 + 2);
        int d2_3 = zy2 + (dx0 + 3) * (dx0 + 3);

        bool n0 = false, n1 = false, n2 = false, n3 = false;
        if (d2_0 <= ro2) { if (d2_0 <= ri2) v0 = slab; else n0 = true; }
        if (d2_1 <= ro2) { if (d2_1 <= ri2) v1 = slab; else n1 = true; }
        if (d2_2 <= ro2) { if (d2_2 <= ri2) v2 = slab; else n2 = true; }
        if (d2_3 <= ro2) { if (d2_3 <= ri2) v3 = slab; else n3 = true; }

        if (n0 | n1 | n2 | n3) {
            // Aligned 16B load of the 4 noise values for this sphere.
            const float4 nz4 = *(const float4*)
                (noise + (((long long)s << 21) + vidx));
            const float frs = (float)sr;
            if (n0) { const float rad = fmaf(nz4.x, 0.5f, frs);
                      if ((float)d2_0 <= rad * rad) v0 = slab; }
            if (n1) { const float rad = fmaf(nz4.y, 0.5f, frs);
                      if ((float)d2_1 <= rad * rad) v1 = slab; }
            if (n2) { const float rad = fmaf(nz4.z, 0.5f, frs);
                      if ((float)d2_2 <= rad * rad) v2 = slab; }
            if (n3) { const float rad = fmaf(nz4.w, 0.5f, frs);
                      if ((float)d2_3 <= rad * rad) v3 = slab; }
        }
    }
    *(float4*)(out + vidx) = make_float4(v0, v1, v2, v3);
}

extern "C" void kernel_launch(void* const* d_in, const int* in_sizes, int n_in,
                              void* d_out, int out_size, void* d_ws, size_t ws_size,
                              hipStream_t stream) {
    const float* noise   = (const float*)d_in[0];
    const float* labels  = (const float*)d_in[1];
    const int*   centers = (const int*)d_in[2];
    const int*   radii   = (const int*)d_in[3];
    float*       out     = (float*)d_out;

    const int n_blocks = SPHERE_STRIDE / 1024;  // 2048 blocks x 256 threads
    sphere_sampler_kernel<<<n_blocks, 256, 0, stream>>>(
        noise, labels, centers, radii, out);
}